// Round 1
// baseline (1402.518 us; speedup 1.0000x reference)
//
#include <hip/hip_runtime.h>

#define N_NODES  50000
#define N_EDGES  500000
#define N_GRAPHS 2000
#define HID      145
#define HID2     72
#define N_LAYERS 4
#define EPS      1e-5f

// ---------------- CSR build ----------------

__global__ void k_hist(const int* __restrict__ col, int* __restrict__ hist) {
    int i = blockIdx.x * 256 + threadIdx.x;
    if (i < N_EDGES) atomicAdd(&hist[col[i]], 1);
}

__global__ void k_dis(const int* __restrict__ hist, float* __restrict__ dis) {
    int i = blockIdx.x * 256 + threadIdx.x;
    if (i < N_NODES) dis[i] = rsqrtf((float)(hist[i] + 1));  // +1 self loop
}

__global__ void k_scan1(const int* __restrict__ cnt, int* __restrict__ incl,
                        int* __restrict__ part) {
    __shared__ int s[1024];
    int i = blockIdx.x * 1024 + threadIdx.x;
    int v = (i < N_NODES) ? cnt[i] : 0;
    s[threadIdx.x] = v;
    __syncthreads();
    for (int d = 1; d < 1024; d <<= 1) {
        int t = (threadIdx.x >= d) ? s[threadIdx.x - d] : 0;
        __syncthreads();
        s[threadIdx.x] += t;
        __syncthreads();
    }
    if (i < N_NODES) incl[i] = s[threadIdx.x];
    if (threadIdx.x == 1023) part[blockIdx.x] = s[1023];
}

__global__ void k_scan2(int* part, int nb) {
    if (threadIdx.x == 0 && blockIdx.x == 0) {
        int acc = 0;
        for (int b = 0; b < nb; b++) { int t = part[b]; part[b] = acc; acc += t; }
    }
}

__global__ void k_scan3(const int* __restrict__ incl, const int* __restrict__ cnt,
                        const int* __restrict__ part, int* __restrict__ starts,
                        int* __restrict__ cursor) {
    int i = blockIdx.x * 1024 + threadIdx.x;
    if (i < N_NODES) {
        int st = incl[i] - cnt[i] + part[blockIdx.x];
        starts[i] = st;
        cursor[i] = st;
    }
    if (i == 0) starts[N_NODES] = N_EDGES;
}

__global__ void k_fill(const int* __restrict__ rowv, const int* __restrict__ colv,
                       int* __restrict__ cursor, int* __restrict__ csr) {
    int e = blockIdx.x * 256 + threadIdx.x;
    if (e < N_EDGES) {
        int c = colv[e];
        int p = atomicAdd(&cursor[c], 1);
        csr[p] = rowv[e];
    }
}

// ---------------- embedding ----------------

__global__ void k_embed(const int* __restrict__ x, const float* __restrict__ emb,
                        float* __restrict__ h) {
    int i = blockIdx.x * 256 + threadIdx.x;
    if (i >= N_NODES * HID) return;
    int n = i / HID;
    int f = i - n * HID;
    h[i] = emb[x[n] * HID + f];
}

// ---------------- GEMM: hw = h @ W (per layer) ----------------
// thread per row; W accesses are wave-uniform -> scalar loads; acc in VGPRs.

template <int C0, int NC>
__global__ __launch_bounds__(256) void k_gemm(const float* __restrict__ h,
                                              const float* __restrict__ W,
                                              float* __restrict__ hw) {
    int r = blockIdx.x * 256 + threadIdx.x;
    if (r >= N_NODES) return;
    const float* hr = h + (size_t)r * HID;
    float acc[NC];
#pragma unroll
    for (int c = 0; c < NC; c++) acc[c] = 0.f;
    for (int k = 0; k < HID; k++) {
        float a = hr[k];
#pragma unroll
        for (int c = 0; c < NC; c++) acc[c] = fmaf(a, W[k * HID + C0 + c], acc[c]);
    }
    float* o = hw + (size_t)r * HID + C0;
#pragma unroll
    for (int c = 0; c < NC; c++) o[c] = acc[c];
}

// ---------------- aggregate: agg[i] = sum_{e: col=i} hw[row]*dis[row]*dis[i] + hw[i]*dis[i]^2
// one wave per node; lanes cover features in 3 chunks (64,64,17). No atomics (CSR).

__global__ __launch_bounds__(256) void k_agg(const float* __restrict__ hw,
                                             const int* __restrict__ starts,
                                             const int* __restrict__ csr,
                                             const float* __restrict__ dis,
                                             float* __restrict__ agg) {
    int wave = threadIdx.x >> 6;
    int lane = threadIdx.x & 63;
    int i = blockIdx.x * 4 + wave;
    if (i >= N_NODES) return;
    float di = dis[i];
    int s = starts[i], e = starts[i + 1];
    int f0 = lane, f1 = lane + 64, f2 = lane + 128;
    float a0 = 0.f, a1 = 0.f, a2 = 0.f;
    for (int j = s; j < e; j++) {
        int src = csr[j];
        float w = dis[src] * di;
        const float* hr = hw + (size_t)src * HID;
        a0 = fmaf(hr[f0], w, a0);
        a1 = fmaf(hr[f1], w, a1);
        if (f2 < HID) a2 = fmaf(hr[f2], w, a2);
    }
    const float* hi = hw + (size_t)i * HID;
    float wi = di * di;
    a0 = fmaf(hi[f0], wi, a0);
    a1 = fmaf(hi[f1], wi, a1);
    if (f2 < HID) a2 = fmaf(hi[f2], wi, a2);
    float* o = agg + (size_t)i * HID;
    o[f0] = a0;
    o[f1] = a1;
    if (f2 < HID) o[f2] = a2;
}

// ---------------- BatchNorm ----------------

__global__ void k_bnstat(const float* __restrict__ agg, float* __restrict__ gsum,
                         float* __restrict__ gsq) {
    __shared__ float ss[HID], sq[HID];
    int t = threadIdx.x;
    if (t < HID) { ss[t] = 0.f; sq[t] = 0.f; }
    __syncthreads();
    const int total = N_NODES * HID;
    for (int i = blockIdx.x * blockDim.x + t; i < total; i += gridDim.x * blockDim.x) {
        float v = agg[i];
        int f = i % HID;
        atomicAdd(&ss[f], v);
        atomicAdd(&sq[f], v * v);
    }
    __syncthreads();
    if (t < HID) {
        atomicAdd(&gsum[t], ss[t]);
        atomicAdd(&gsq[t], sq[t]);
    }
}

__global__ void k_bncoef(const float* __restrict__ gsum, const float* __restrict__ gsq,
                         const float* __restrict__ gamma, const float* __restrict__ beta,
                         float* __restrict__ A, float* __restrict__ B) {
    int f = threadIdx.x;
    if (f >= HID) return;
    const float inv = 1.f / (float)N_NODES;
    float mu = gsum[f] * inv;
    float var = gsq[f] * inv - mu * mu;
    float rstd = rsqrtf(var + EPS);
    float a = gamma[f] * rstd;
    A[f] = a;
    B[f] = beta[f] - mu * a;
}

__global__ void k_bnapply(const float* __restrict__ agg, const float* __restrict__ A,
                          const float* __restrict__ B, float* __restrict__ h) {
    int i = blockIdx.x * 256 + threadIdx.x;
    if (i >= N_NODES * HID) return;
    int f = i % HID;
    float v = fmaf(A[f], agg[i], B[f]);
    v = fmaxf(v, 0.f);
    h[i] = v + h[i];  // relu + residual, in place (h holds h_in)
}

// ---------------- pooling + MLP ----------------

__global__ __launch_bounds__(256) void k_pool(const float* __restrict__ h,
                                              const int* __restrict__ batch,
                                              float* __restrict__ hg) {
    int g = blockIdx.x;
    // lower_bound(batch, g) and lower_bound(batch, g+1) on sorted batch_idx
    int lo = 0, hi = N_NODES;
    while (lo < hi) { int m = (lo + hi) >> 1; if (batch[m] < g) lo = m + 1; else hi = m; }
    int s = lo;
    hi = N_NODES;
    while (lo < hi) { int m = (lo + hi) >> 1; if (batch[m] < g + 1) lo = m + 1; else hi = m; }
    int e = lo;
    int f = threadIdx.x;
    if (f >= HID) return;
    float acc = 0.f;
    for (int n = s; n < e; n++) acc += h[(size_t)n * HID + f];
    float cnt = (float)(e - s);
    hg[g * HID + f] = acc / fmaxf(cnt, 1.f);
}

__global__ __launch_bounds__(128) void k_mlp(const float* __restrict__ hg,
                                             const float* __restrict__ W1,
                                             const float* __restrict__ b1,
                                             const float* __restrict__ W2,
                                             const float* __restrict__ b2,
                                             float* __restrict__ out) {
    int g = blockIdx.x;
    int t = threadIdx.x;
    float v = 0.f;
    if (t < HID2) {
        float s = b1[t];
        const float* hgr = hg + g * HID;
        for (int k = 0; k < HID; k++) s = fmaf(hgr[k], W1[k * HID2 + t], s);
        v = fmaxf(s, 0.f) * W2[t];
    }
    __shared__ float red[128];
    red[t] = v;
    __syncthreads();
    for (int d = 64; d > 0; d >>= 1) {
        if (t < d) red[t] += red[t + d];
        __syncthreads();
    }
    if (t == 0) out[g] = red[0] + b2[0];
}

// ---------------- host launch ----------------

extern "C" void kernel_launch(void* const* d_in, const int* in_sizes, int n_in,
                              void* d_out, int out_size, void* d_ws, size_t ws_size,
                              hipStream_t stream) {
    const int*   x     = (const int*)d_in[0];
    const int*   erow  = (const int*)d_in[1];
    const int*   ecol  = erow + N_EDGES;
    const int*   batch = (const int*)d_in[2];
    const float* emb   = (const float*)d_in[3];
    const float* Wc    = (const float*)d_in[4];
    // d_in[5] = bc: unused — BatchNorm is invariant to per-feature constant shift
    const float* gamma = (const float*)d_in[6];
    const float* beta  = (const float*)d_in[7];
    const float* W1    = (const float*)d_in[8];
    const float* b1    = (const float*)d_in[9];
    const float* W2    = (const float*)d_in[10];
    const float* b2    = (const float*)d_in[11];
    float* out = (float*)d_out;

    char* wsb = (char*)d_ws;
    size_t off = 0;
    auto alloc = [&](size_t bytes) -> char* {
        char* p = wsb + off;
        off = (off + bytes + 255) & ~(size_t)255;
        return p;
    };
    int*   hist   = (int*)alloc(N_NODES * 4);
    int*   incl   = (int*)alloc(N_NODES * 4);
    int*   part   = (int*)alloc(64 * 4);
    int*   starts = (int*)alloc((N_NODES + 1) * 4);
    int*   cursor = (int*)alloc(N_NODES * 4);
    int*   csr    = (int*)alloc(N_EDGES * 4);
    float* dis    = (float*)alloc(N_NODES * 4);
    float* h      = (float*)alloc((size_t)N_NODES * HID * 4);
    float* hw     = (float*)alloc((size_t)N_NODES * HID * 4);
    float* agg    = (float*)alloc((size_t)N_NODES * HID * 4);
    float* gsum   = (float*)alloc(2 * HID * 4);  // gsum + gsq contiguous
    float* gsq    = gsum + HID;
    float* A      = (float*)alloc(2 * HID * 4);
    float* B      = A + HID;
    float* hg     = (float*)alloc((size_t)N_GRAPHS * HID * 4);

    const int NB_SCAN = (N_NODES + 1023) / 1024;  // 49

    // CSR build (reused across all layers)
    hipMemsetAsync(hist, 0, N_NODES * 4, stream);
    k_hist<<<(N_EDGES + 255) / 256, 256, 0, stream>>>(ecol, hist);
    k_dis<<<(N_NODES + 255) / 256, 256, 0, stream>>>(hist, dis);
    k_scan1<<<NB_SCAN, 1024, 0, stream>>>(hist, incl, part);
    k_scan2<<<1, 64, 0, stream>>>(part, NB_SCAN);
    k_scan3<<<NB_SCAN, 1024, 0, stream>>>(incl, hist, part, starts, cursor);
    k_fill<<<(N_EDGES + 255) / 256, 256, 0, stream>>>(erow, ecol, cursor, csr);

    // embedding
    const int NEL = N_NODES * HID;
    k_embed<<<(NEL + 255) / 256, 256, 0, stream>>>(x, emb, h);

    for (int l = 0; l < N_LAYERS; l++) {
        const float* Wl = Wc + (size_t)l * HID * HID;
        k_gemm<0, 73><<<(N_NODES + 255) / 256, 256, 0, stream>>>(h, Wl, hw);
        k_gemm<73, 72><<<(N_NODES + 255) / 256, 256, 0, stream>>>(h, Wl, hw);
        k_agg<<<(N_NODES + 3) / 4, 256, 0, stream>>>(hw, starts, csr, dis, agg);
        hipMemsetAsync(gsum, 0, 2 * HID * 4, stream);
        k_bnstat<<<512, 256, 0, stream>>>(agg, gsum, gsq);
        k_bncoef<<<1, 256, 0, stream>>>(gsum, gsq, gamma + l * HID, beta + l * HID, A, B);
        k_bnapply<<<(NEL + 255) / 256, 256, 0, stream>>>(agg, A, B, h);
    }

    k_pool<<<N_GRAPHS, 256, 0, stream>>>(h, batch, hg);
    k_mlp<<<N_GRAPHS, 128, 0, stream>>>(hg, W1, b1, W2, b2, out);
}

// Round 2
// 957.982 us; speedup vs baseline: 1.4640x; 1.4640x over previous
//
#include <hip/hip_runtime.h>

#define N_NODES  50000
#define N_EDGES  500000
#define N_GRAPHS 2000
#define HID      145
#define HID2     72
#define N_LAYERS 4
#define EPS      1e-5f
#define HWS_LD   160   // padded row stride for gather target: 640B = 5 aligned 128B lines
#define BR       128   // rows per GEMM block
#define NSTAT    256   // bnstat partial blocks

// ---------------- CSR build ----------------

__global__ void k_hist(const int* __restrict__ col, int* __restrict__ hist) {
    int i = blockIdx.x * 256 + threadIdx.x;
    if (i < N_EDGES) atomicAdd(&hist[col[i]], 1);
}

__global__ void k_scan1(const int* __restrict__ cnt, int* __restrict__ incl,
                        int* __restrict__ part) {
    __shared__ int s[1024];
    int i = blockIdx.x * 1024 + threadIdx.x;
    int v = (i < N_NODES) ? cnt[i] : 0;
    s[threadIdx.x] = v;
    __syncthreads();
    for (int d = 1; d < 1024; d <<= 1) {
        int t = (threadIdx.x >= d) ? s[threadIdx.x - d] : 0;
        __syncthreads();
        s[threadIdx.x] += t;
        __syncthreads();
    }
    if (i < N_NODES) incl[i] = s[threadIdx.x];
    if (threadIdx.x == 1023) part[blockIdx.x] = s[1023];
}

__global__ void k_scan2(int* part, int nb) {
    if (threadIdx.x == 0 && blockIdx.x == 0) {
        int acc = 0;
        for (int b = 0; b < nb; b++) { int t = part[b]; part[b] = acc; acc += t; }
    }
}

__global__ void k_scan3(const int* __restrict__ incl, const int* __restrict__ cnt,
                        const int* __restrict__ part, int* __restrict__ starts,
                        int* __restrict__ cursor, float* __restrict__ dis) {
    int i = blockIdx.x * 1024 + threadIdx.x;
    if (i < N_NODES) {
        int st = incl[i] - cnt[i] + part[blockIdx.x];
        starts[i] = st;
        cursor[i] = st;
        dis[i] = rsqrtf((float)(cnt[i] + 1));  // +1 self loop
    }
    if (i == 0) starts[N_NODES] = N_EDGES;
}

__global__ void k_fill(const int* __restrict__ rowv, const int* __restrict__ colv,
                       int* __restrict__ cursor, int* __restrict__ csr) {
    int e = blockIdx.x * 256 + threadIdx.x;
    if (e < N_EDGES) {
        int c = colv[e];
        int p = atomicAdd(&cursor[c], 1);
        csr[p] = rowv[e];
    }
}

// ---------------- fused (BN-apply | embed) + GEMM ----------------
// Phase 1: h_new = relu(A*agg+B) + h_old (in place, MODE 1) or emb[x] (MODE 0),
//          written to global h and LDS tile (stride 145 floats: odd -> bank-free).
// Phase 2: thread-per-row, 2 wave-uniform col chunks of 73 (col 72 duplicated),
//          W loads scalar (uniform via readfirstlane), epilogue scales by dis.

template <int MODE>
__global__ __launch_bounds__(256) void k_gemm_fused(
    const float* __restrict__ Wl, const float* __restrict__ dis,
    const int* __restrict__ x, const float* __restrict__ emb,
    const float* __restrict__ agg, const float* __restrict__ AB,
    float* __restrict__ h, float* __restrict__ hws) {
    __shared__ float tile[BR * HID];
    __shared__ float sA[HID], sB[HID];
    int t = threadIdx.x;
    int rbase = blockIdx.x * BR;
    if (MODE == 1 && t < HID) { sA[t] = AB[t]; sB[t] = AB[HID + t]; }
    __syncthreads();
    for (int e = t; e < BR * HID; e += 256) {
        int r = e / HID;
        int f = e - r * HID;
        int gr = rbase + r;
        float v = 0.f;
        if (gr < N_NODES) {
            size_t idx = (size_t)gr * HID + f;
            if (MODE == 0) {
                v = emb[x[gr] * HID + f];
            } else {
                v = fmaf(sA[f], agg[idx], sB[f]);
                v = fmaxf(v, 0.f) + h[idx];
            }
            h[idx] = v;
        }
        tile[e] = v;
    }
    __syncthreads();
    int row = t & (BR - 1);
    int c0 = __builtin_amdgcn_readfirstlane((t >> 7) * 72);  // wave-uniform: 0 or 72
    int gr = rbase + row;
    float acc[73];
#pragma unroll
    for (int c = 0; c < 73; c++) acc[c] = 0.f;
    const float* tr = tile + row * HID;
    for (int k = 0; k < HID; k++) {
        float a = tr[k];
        const float* wr = Wl + k * HID + c0;
#pragma unroll
        for (int c = 0; c < 73; c++) acc[c] = fmaf(a, wr[c], acc[c]);
    }
    if (gr < N_NODES) {
        float d = dis[gr];
        float* o = hws + (size_t)gr * HWS_LD + c0;
#pragma unroll
        for (int c = 0; c < 73; c++) o[c] = acc[c] * d;
    }
}

// ---------------- aggregate: agg[i] = dis[i] * (sum_{src in N(i)} hws[src] + hws[i])
// one wave per node, unroll 4 edges -> 12 row-loads in flight.

__global__ __launch_bounds__(256) void k_agg(const float* __restrict__ hws,
                                             const int* __restrict__ starts,
                                             const int* __restrict__ csr,
                                             const float* __restrict__ dis,
                                             float* __restrict__ agg) {
    int wave = threadIdx.x >> 6;
    int lane = threadIdx.x & 63;
    int i = blockIdx.x * 4 + wave;
    if (i >= N_NODES) return;
    int s = starts[i], e = starts[i + 1];
    int f0 = lane, f1 = lane + 64, f2 = lane + 128;
    bool p2 = f2 < HID;
    const float* self = hws + (size_t)i * HWS_LD;
    float a0 = self[f0];
    float a1 = self[f1];
    float a2 = p2 ? self[f2] : 0.f;
    int j = s;
    for (; j + 4 <= e; j += 4) {
        int s0 = csr[j], s1 = csr[j + 1], s2 = csr[j + 2], s3 = csr[j + 3];
        const float* q0 = hws + (size_t)s0 * HWS_LD;
        const float* q1 = hws + (size_t)s1 * HWS_LD;
        const float* q2 = hws + (size_t)s2 * HWS_LD;
        const float* q3 = hws + (size_t)s3 * HWS_LD;
        float b00 = q0[f0], b10 = q1[f0], b20 = q2[f0], b30 = q3[f0];
        float b01 = q0[f1], b11 = q1[f1], b21 = q2[f1], b31 = q3[f1];
        float b02 = p2 ? q0[f2] : 0.f, b12 = p2 ? q1[f2] : 0.f;
        float b22 = p2 ? q2[f2] : 0.f, b32 = p2 ? q3[f2] : 0.f;
        a0 += (b00 + b10) + (b20 + b30);
        a1 += (b01 + b11) + (b21 + b31);
        a2 += (b02 + b12) + (b22 + b32);
    }
    for (; j < e; j++) {
        const float* q = hws + (size_t)csr[j] * HWS_LD;
        a0 += q[f0];
        a1 += q[f1];
        if (p2) a2 += q[f2];
    }
    float di = dis[i];
    float* o = agg + (size_t)i * HID;
    o[f0] = a0 * di;
    o[f1] = a1 * di;
    if (p2) o[f2] = a2 * di;
}

// ---------------- BatchNorm stats: per-block register accumulation ----------------

__global__ __launch_bounds__(192) void k_bnstat(const float* __restrict__ agg,
                                                float* __restrict__ partial) {
    int t = threadIdx.x;
    if (t >= HID) return;
    float s = 0.f, q = 0.f;
    for (int r = blockIdx.x; r < N_NODES; r += NSTAT) {
        float v = agg[(size_t)r * HID + t];
        s += v;
        q = fmaf(v, v, q);
    }
    partial[blockIdx.x * (2 * HID) + t] = s;
    partial[blockIdx.x * (2 * HID) + HID + t] = q;
}

__global__ __launch_bounds__(192) void k_bncoef(const float* __restrict__ partial,
                                                const float* __restrict__ gamma,
                                                const float* __restrict__ beta,
                                                float* __restrict__ AB) {
    int f = threadIdx.x;
    if (f >= HID) return;
    float s = 0.f, q = 0.f;
    for (int b = 0; b < NSTAT; b++) {
        s += partial[b * (2 * HID) + f];
        q += partial[b * (2 * HID) + HID + f];
    }
    const float inv = 1.f / (float)N_NODES;
    float mu = s * inv;
    float var = q * inv - mu * mu;
    float a = gamma[f] * rsqrtf(var + EPS);
    AB[f] = a;
    AB[HID + f] = beta[f] - mu * a;
}

// ---------------- pool (fused with layer-3 BN apply) + MLP ----------------

__global__ __launch_bounds__(192) void k_pool(const float* __restrict__ agg,
                                              const float* __restrict__ h,
                                              const float* __restrict__ AB,
                                              const int* __restrict__ batch,
                                              float* __restrict__ hg) {
    int g = blockIdx.x;
    int lo = 0, hi = N_NODES;
    while (lo < hi) { int m = (lo + hi) >> 1; if (batch[m] < g) lo = m + 1; else hi = m; }
    int s = lo;
    hi = N_NODES;
    while (lo < hi) { int m = (lo + hi) >> 1; if (batch[m] < g + 1) lo = m + 1; else hi = m; }
    int e = lo;
    int f = threadIdx.x;
    if (f >= HID) return;
    float A = AB[f], B = AB[HID + f];
    float acc = 0.f;
    for (int n = s; n < e; n++) {
        size_t idx = (size_t)n * HID + f;
        float v = fmaf(A, agg[idx], B);
        acc += fmaxf(v, 0.f) + h[idx];
    }
    hg[g * HID + f] = acc / fmaxf((float)(e - s), 1.f);
}

__global__ __launch_bounds__(128) void k_mlp(const float* __restrict__ hg,
                                             const float* __restrict__ W1,
                                             const float* __restrict__ b1,
                                             const float* __restrict__ W2,
                                             const float* __restrict__ b2,
                                             float* __restrict__ out) {
    int g = blockIdx.x;
    int t = threadIdx.x;
    float v = 0.f;
    if (t < HID2) {
        float s = b1[t];
        const float* hgr = hg + g * HID;
        for (int k = 0; k < HID; k++) s = fmaf(hgr[k], W1[k * HID2 + t], s);
        v = fmaxf(s, 0.f) * W2[t];
    }
    __shared__ float red[128];
    red[t] = v;
    __syncthreads();
    for (int d = 64; d > 0; d >>= 1) {
        if (t < d) red[t] += red[t + d];
        __syncthreads();
    }
    if (t == 0) out[g] = red[0] + b2[0];
}

// ---------------- host launch ----------------

extern "C" void kernel_launch(void* const* d_in, const int* in_sizes, int n_in,
                              void* d_out, int out_size, void* d_ws, size_t ws_size,
                              hipStream_t stream) {
    const int*   x     = (const int*)d_in[0];
    const int*   erow  = (const int*)d_in[1];
    const int*   ecol  = erow + N_EDGES;
    const int*   batch = (const int*)d_in[2];
    const float* emb   = (const float*)d_in[3];
    const float* Wc    = (const float*)d_in[4];
    // d_in[5] = bc: unused — BatchNorm cancels a per-feature constant shift
    const float* gamma = (const float*)d_in[6];
    const float* beta  = (const float*)d_in[7];
    const float* W1    = (const float*)d_in[8];
    const float* b1    = (const float*)d_in[9];
    const float* W2    = (const float*)d_in[10];
    const float* b2    = (const float*)d_in[11];
    float* out = (float*)d_out;

    char* wsb = (char*)d_ws;
    size_t off = 0;
    auto alloc = [&](size_t bytes) -> char* {
        char* p = wsb + off;
        off = (off + bytes + 255) & ~(size_t)255;
        return p;
    };
    int*   hist    = (int*)alloc(N_NODES * 4);
    int*   incl    = (int*)alloc(N_NODES * 4);
    int*   part    = (int*)alloc(64 * 4);
    int*   starts  = (int*)alloc((N_NODES + 1) * 4);
    int*   cursor  = (int*)alloc(N_NODES * 4);
    int*   csr     = (int*)alloc(N_EDGES * 4);
    float* dis     = (float*)alloc(N_NODES * 4);
    float* h       = (float*)alloc((size_t)N_NODES * HID * 4);
    float* hws     = (float*)alloc((size_t)N_NODES * HWS_LD * 4);
    float* agg     = (float*)alloc((size_t)N_NODES * HID * 4);
    float* partial = (float*)alloc((size_t)NSTAT * 2 * HID * 4);
    float* AB      = (float*)alloc(2 * HID * 4);
    float* hg      = (float*)alloc((size_t)N_GRAPHS * HID * 4);

    const int NB_SCAN = (N_NODES + 1023) / 1024;  // 49
    const int NB_GEMM = (N_NODES + BR - 1) / BR;  // 391

    // CSR build (reused across all layers)
    hipMemsetAsync(hist, 0, N_NODES * 4, stream);
    k_hist<<<(N_EDGES + 255) / 256, 256, 0, stream>>>(ecol, hist);
    k_scan1<<<NB_SCAN, 1024, 0, stream>>>(hist, incl, part);
    k_scan2<<<1, 64, 0, stream>>>(part, NB_SCAN);
    k_scan3<<<NB_SCAN, 1024, 0, stream>>>(incl, hist, part, starts, cursor, dis);
    k_fill<<<(N_EDGES + 255) / 256, 256, 0, stream>>>(erow, ecol, cursor, csr);

    for (int l = 0; l < N_LAYERS; l++) {
        const float* Wl = Wc + (size_t)l * HID * HID;
        if (l == 0)
            k_gemm_fused<0><<<NB_GEMM, 256, 0, stream>>>(Wl, dis, x, emb, agg, AB, h, hws);
        else
            k_gemm_fused<1><<<NB_GEMM, 256, 0, stream>>>(Wl, dis, x, emb, agg, AB, h, hws);
        k_agg<<<(N_NODES + 3) / 4, 256, 0, stream>>>(hws, starts, csr, dis, agg);
        k_bnstat<<<NSTAT, 192, 0, stream>>>(agg, partial);
        k_bncoef<<<1, 192, 0, stream>>>(partial, gamma + l * HID, beta + l * HID, AB);
    }

    k_pool<<<N_GRAPHS, 192, 0, stream>>>(agg, h, AB, batch, hg);
    k_mlp<<<N_GRAPHS, 128, 0, stream>>>(hg, W1, b1, W2, b2, out);
}